// Round 7
// baseline (275.344 us; speedup 1.0000x reference)
//
#include <hip/hip_runtime.h>

#define B_ 2
#define T_ 4096
#define E_ 768
#define H_ 12
#define S_ 64
#define WIN_ 256

typedef unsigned short u16;
typedef unsigned int u32;
typedef __attribute__((ext_vector_type(8))) short bf16x8;
typedef __attribute__((ext_vector_type(4))) short bf16x4;
typedef __attribute__((ext_vector_type(4))) float f32x4;

__device__ __forceinline__ u16 f2bf(float f) {
  u32 u = __float_as_uint(f);
  u += ((u >> 16) & 1u) + 0x7fffu;   // RNE
  return (u16)(u >> 16);
}

__device__ __forceinline__ void async_copy16(const u16* g, u16* l) {
  __builtin_amdgcn_global_load_lds(
      (const __attribute__((address_space(1))) void*)g,
      (__attribute__((address_space(3))) void*)l, 16, 0, 0);
}

// ---------------- fp32 -> bf16, all 4 tensors in one dispatch ----------------
__global__ void cvt_all(const float* __restrict__ x, const float* __restrict__ wq,
                        const float* __restrict__ wk, const float* __restrict__ wv,
                        u16* __restrict__ xb, u16* __restrict__ wb) {
  const int n4x = B_ * T_ * E_ / 4;
  const int n4w = E_ * E_ / 4;
  int i = blockIdx.x * 256 + threadIdx.x;
  const float* src;
  u16* dst;
  int j;
  if (i < n4x) {
    src = x; dst = xb; j = i;
  } else {
    int t = i - n4x;
    int z = t / n4w;
    if (z >= 3) return;
    j = t - z * n4w;
    src = (z == 0) ? wq : ((z == 1) ? wk : wv);
    dst = wb + (size_t)z * E_ * E_;
  }
  float4 v = ((const float4*)src)[j];
  ushort4 o;
  o.x = f2bf(v.x); o.y = f2bf(v.y); o.z = f2bf(v.z); o.w = f2bf(v.w);
  ((ushort4*)dst)[j] = o;
}

// ---------------- QKV projection GEMM: 128x64 tile, dbuf, 2304 blocks ----------------
__global__ __launch_bounds__(256, 6)
void gemm_qkv(const u16* __restrict__ xb, const u16* __restrict__ wb,
              u16* __restrict__ qkv) {
  const int M = B_ * T_;
  __shared__ u16 As[2][4][128][8];   // 16KB
  __shared__ u16 Bs[2][4][64][8];    // 8KB
  int tid = threadIdx.x;
  int lane = tid & 63, wave = tid >> 6;
  int wr = wave >> 1, wc = wave & 1;
  int q8 = lane >> 4, nl = lane & 15;
  int bm = blockIdx.x * 128, bn = blockIdx.y * 64;
  int z = blockIdx.z;
  const u16* A = xb;
  const u16* Bmat = wb + (size_t)z * E_ * E_;
  u16* C = qkv + (size_t)z * M * E_;
  float scale = (z == 0) ? (0.125f * 1.44269504088896f) : 1.0f;

  int chA0 = tid >> 7, rowA0 = tid & 127;
  int uA1 = tid + 256;
  int chA1 = uA1 >> 7, rowA1 = uA1 & 127;
  int chB = tid >> 6, rowB = tid & 63;
  const u16* ga0 = A + (size_t)(bm + rowA0) * E_ + chA0 * 8;
  const u16* ga1 = A + (size_t)(bm + rowA1) * E_ + chA1 * 8;
  const u16* gb  = Bmat + (size_t)(bn + rowB) * E_ + chB * 8;

  const int NK = E_ / 32;   // 24

#define STAGE(s, ko)                                   \
  do {                                                 \
    async_copy16(ga0 + (ko), &As[s][chA0][rowA0][0]);  \
    async_copy16(ga1 + (ko), &As[s][chA1][rowA1][0]);  \
    async_copy16(gb + (ko), &Bs[s][chB][rowB][0]);     \
  } while (0)

  STAGE(0, 0);

  f32x4 acc[4][2] = {};
  for (int ki = 0; ki < NK; ++ki) {
    int buf = ki & 1;
    __syncthreads();
    if (ki + 1 < NK) STAGE(buf ^ 1, (ki + 1) * 32);
    bf16x8 af[4], bfr[2];
#pragma unroll
    for (int i = 0; i < 4; ++i)
      af[i] = *(const bf16x8*)&As[buf][q8][wr * 64 + i * 16 + nl][0];
#pragma unroll
    for (int j = 0; j < 2; ++j)
      bfr[j] = *(const bf16x8*)&Bs[buf][q8][wc * 32 + j * 16 + nl][0];
#pragma unroll
    for (int i = 0; i < 4; ++i)
#pragma unroll
      for (int j = 0; j < 2; ++j)
        acc[i][j] = __builtin_amdgcn_mfma_f32_16x16x32_bf16(af[i], bfr[j], acc[i][j], 0, 0, 0);
  }
#undef STAGE

#pragma unroll
  for (int i = 0; i < 4; ++i)
#pragma unroll
    for (int j = 0; j < 2; ++j)
#pragma unroll
      for (int r = 0; r < 4; ++r) {
        int row = bm + wr * 64 + i * 16 + q8 * 4 + r;
        int col = bn + wc * 32 + j * 16 + nl;
        C[(size_t)row * E_ + col] = f2bf(acc[i][j][r] * scale);
      }
}

// ---------------- V transpose: v[b*T+t][e] -> vT[b][e][t] ----------------
__global__ void transpose_v(const u16* __restrict__ v, u16* __restrict__ vT) {
  __shared__ u16 lt[64][66];
  int t = threadIdx.x;
  int t0 = blockIdx.x * 64;
  int e0 = blockIdx.y * 64;
  int b = blockIdx.z;
#pragma unroll
  for (int i = 0; i < 2; ++i) {
    int u = t + i * 256;
    int tok = u >> 3, cg = u & 7;
    bf16x8 val = *(const bf16x8*)(v + (size_t)(b * T_ + t0 + tok) * E_ + e0 + cg * 8);
#pragma unroll
    for (int j = 0; j < 8; ++j) lt[tok][cg * 8 + j] = (u16)val[j];
  }
  __syncthreads();
#pragma unroll
  for (int i = 0; i < 2; ++i) {
    int u = t + i * 256;
    int d = u >> 3, ck = u & 7;
    bf16x8 o;
#pragma unroll
    for (int j = 0; j < 8; ++j) o[j] = (short)lt[ck * 8 + j][d];
    *(bf16x8*)(vT + (size_t)(b * E_ + e0 + d) * T_ + t0 + ck * 8) = o;
  }
}

// ---------------- banded flash attention: 16 queries/wave, barrier-free ----------------
__global__ __launch_bounds__(256)
void attn_kernel(const u16* __restrict__ qkv, const u16* __restrict__ vT,
                 float* __restrict__ out) {
  const int Mtot = B_ * T_;
  const u16* qb = qkv;
  const u16* kb = qkv + (size_t)Mtot * E_;

  __shared__ u16 Pl[4][16][36];

  int tid = threadIdx.x;
  int lane = tid & 63, wave = tid >> 6;
  int q8 = lane >> 4, nl = lane & 15;
  int qs = blockIdx.x * 64;
  int bh = blockIdx.y;
  int b = bh / H_, h = bh % H_;
  int qw = qs + wave * 16;
  size_t ho = (size_t)h * S_;

  bf16x8 aq[2];
  {
    const u16* qrow = qb + (size_t)(b * T_ + qw + nl) * E_ + ho;
    aq[0] = *(const bf16x8*)(qrow + q8 * 8);
    aq[1] = *(const bf16x8*)(qrow + 32 + q8 * 8);
  }

  f32x4 O[4] = {};
  f32x4 lacc = {};

  int klo = qw - WIN_; if (klo < 0) klo = 0;
  int khi = qw + 16 + WIN_; if (khi > T_) khi = T_;

  const u16* kbase = kb + (size_t)b * T_ * E_ + ho;
  const u16* vbase = vT + (size_t)b * E_ * T_ + ho * T_;

  bf16x8 bk[2][2];
#pragma unroll
  for (int nt = 0; nt < 2; ++nt) {
    const u16* krow = kbase + (size_t)(klo + nt * 16 + nl) * E_;
    bk[nt][0] = *(const bf16x8*)(krow + q8 * 8);
    bk[nt][1] = *(const bf16x8*)(krow + 32 + q8 * 8);
  }

  for (int kt = klo; kt < khi; kt += 32) {
    bf16x8 bv[4];
#pragma unroll
    for (int dt = 0; dt < 4; ++dt)
      bv[dt] = *(const bf16x8*)(vbase + (size_t)(dt * 16 + nl) * T_ + kt + q8 * 8);

    int ktn = (kt + 32 < khi) ? kt + 32 : kt;
    bf16x8 nbk[2][2];
#pragma unroll
    for (int nt = 0; nt < 2; ++nt) {
      const u16* krow = kbase + (size_t)(ktn + nt * 16 + nl) * E_;
      nbk[nt][0] = *(const bf16x8*)(krow + q8 * 8);
      nbk[nt][1] = *(const bf16x8*)(krow + 32 + q8 * 8);
    }

    f32x4 sc[2] = {};
#pragma unroll
    for (int nt = 0; nt < 2; ++nt) {
      sc[nt] = __builtin_amdgcn_mfma_f32_16x16x32_bf16(aq[0], bk[nt][0], sc[nt], 0, 0, 0);
      sc[nt] = __builtin_amdgcn_mfma_f32_16x16x32_bf16(aq[1], bk[nt][1], sc[nt], 0, 0, 0);
    }

    // edge mask: band edges OR tile crossing the T boundary (unaligned clamp:
    // odd waves have qw≡16 mod 32, so the last tile can cover keys >= T_)
    if (kt < qw - 241 || kt > qw + 225 || kt + 31 >= T_) {
#pragma unroll
      for (int nt = 0; nt < 2; ++nt)
#pragma unroll
        for (int r = 0; r < 4; ++r) {
          int qa = qw + q8 * 4 + r;
          int ka = kt + nt * 16 + nl;
          int d = ka - qa;
          sc[nt][r] = (d < -WIN_ || d > WIN_ || ka >= T_) ? -1e30f : sc[nt][r];
        }
    }

#pragma unroll
    for (int r = 0; r < 4; ++r) {
      float p0 = exp2f(sc[0][r]);
      float p1 = exp2f(sc[1][r]);
      sc[0][r] = p0; sc[1][r] = p1;
      lacc[r] += p0 + p1;
    }

#pragma unroll
    for (int r = 0; r < 4; ++r) {
      Pl[wave][q8 * 4 + r][nl] = f2bf(sc[0][r]);
      Pl[wave][q8 * 4 + r][16 + nl] = f2bf(sc[1][r]);
    }
    bf16x8 ap;
    {
      bf16x4 lo = *(const bf16x4*)&Pl[wave][nl][q8 * 8];
      bf16x4 hi = *(const bf16x4*)&Pl[wave][nl][q8 * 8 + 4];
      ap[0] = lo[0]; ap[1] = lo[1]; ap[2] = lo[2]; ap[3] = lo[3];
      ap[4] = hi[0]; ap[5] = hi[1]; ap[6] = hi[2]; ap[7] = hi[3];
    }

#pragma unroll
    for (int dt = 0; dt < 4; ++dt)
      O[dt] = __builtin_amdgcn_mfma_f32_16x16x32_bf16(ap, bv[dt], O[dt], 0, 0, 0);

#pragma unroll
    for (int nt = 0; nt < 2; ++nt) {
      bk[nt][0] = nbk[nt][0];
      bk[nt][1] = nbk[nt][1];
    }
  }

#pragma unroll
  for (int r = 0; r < 4; ++r) {
    float l = lacc[r];
    l += __shfl_xor(l, 1); l += __shfl_xor(l, 2);
    l += __shfl_xor(l, 4); l += __shfl_xor(l, 8);
    float inv = 1.0f / l;
    int qa = qw + q8 * 4 + r;
    float* op = out + (size_t)(b * T_ + qa) * E_ + ho;
#pragma unroll
    for (int dt = 0; dt < 4; ++dt)
      op[dt * 16 + nl] = O[dt][r] * inv;
  }
}

extern "C" void kernel_launch(void* const* d_in, const int* in_sizes, int n_in,
                              void* d_out, int out_size, void* d_ws, size_t ws_size,
                              hipStream_t stream) {
  const float* x  = (const float*)d_in[0];
  const float* Wq = (const float*)d_in[1];
  const float* Wk = (const float*)d_in[2];
  const float* Wv = (const float*)d_in[3];
  float* out = (float*)d_out;

  const size_t M = (size_t)B_ * T_;
  u16* xb  = (u16*)d_ws;               // M*E bf16; reused as vT after gemm
  u16* wb  = xb + M * E_;              // 3*E*E
  u16* qkv = wb + 3 * (size_t)E_ * E_; // 3*M*E
  u16* vT  = xb;                       // [B][E][T]

  const int n4x = B_ * T_ * E_ / 4;
  const int n4w = E_ * E_ / 4;
  int cvt_blocks = (n4x + 3 * n4w + 255) / 256;
  cvt_all<<<cvt_blocks, 256, 0, stream>>>(x, Wq, Wk, Wv, xb, wb);

  dim3 g1(M / 128, E_ / 64, 3);
  gemm_qkv<<<g1, 256, 0, stream>>>(xb, wb, qkv);

  dim3 gt(T_ / 64, E_ / 64, B_);
  transpose_v<<<gt, 256, 0, stream>>>(qkv + 2 * M * E_, vT);

  dim3 g2(T_ / 64, B_ * H_);
  attn_kernel<<<g2, 256, 0, stream>>>(qkv, vT, out);
}

// Round 8
// 253.772 us; speedup vs baseline: 1.0850x; 1.0850x over previous
//
#include <hip/hip_runtime.h>

#define B_ 2
#define T_ 4096
#define E_ 768
#define H_ 12
#define S_ 64
#define WIN_ 256

typedef unsigned short u16;
typedef unsigned int u32;
typedef __attribute__((ext_vector_type(8))) short bf16x8;
typedef __attribute__((ext_vector_type(4))) short bf16x4;
typedef __attribute__((ext_vector_type(4))) float f32x4;

__device__ __forceinline__ u16 f2bf(float f) {
  u32 u = __float_as_uint(f);
  u += ((u >> 16) & 1u) + 0x7fffu;   // RNE
  return (u16)(u >> 16);
}

__device__ __forceinline__ void async_copy16(const u16* g, u16* l) {
  __builtin_amdgcn_global_load_lds(
      (const __attribute__((address_space(1))) void*)g,
      (__attribute__((address_space(3))) void*)l, 16, 0, 0);
}

// ---------------- fp32 -> bf16, all 4 tensors in one dispatch ----------------
__global__ void cvt_all(const float* __restrict__ x, const float* __restrict__ wq,
                        const float* __restrict__ wk, const float* __restrict__ wv,
                        u16* __restrict__ xb, u16* __restrict__ wb) {
  const int n4x = B_ * T_ * E_ / 4;
  const int n4w = E_ * E_ / 4;
  int i = blockIdx.x * 256 + threadIdx.x;
  const float* src;
  u16* dst;
  int j;
  if (i < n4x) {
    src = x; dst = xb; j = i;
  } else {
    int t = i - n4x;
    int z = t / n4w;
    if (z >= 3) return;
    j = t - z * n4w;
    src = (z == 0) ? wq : ((z == 1) ? wk : wv);
    dst = wb + (size_t)z * E_ * E_;
  }
  float4 v = ((const float4*)src)[j];
  ushort4 o;
  o.x = f2bf(v.x); o.y = f2bf(v.y); o.z = f2bf(v.z); o.w = f2bf(v.w);
  ((ushort4*)dst)[j] = o;
}

// ---------------- QKV projection GEMM: BM=256, BN=64, dbuf ----------------
// Reuse fix: logical cache traffic 264 MB vs 453 MB at 128x128 (A re-read 12x
// instead of 6x but B re-read 32x instead of 64x; A term smaller). Grid still
// 1152 blocks (4.5/CU supply); LDS 40KB -> 4 blocks/CU resident.
__global__ __launch_bounds__(256)
void gemm_qkv(const u16* __restrict__ xb, const u16* __restrict__ wb,
              u16* __restrict__ qkv) {
  const int M = B_ * T_;
  __shared__ u16 As[2][4][256][8];   // 32KB
  __shared__ u16 Bs[2][4][64][8];    // 8KB
  int tid = threadIdx.x;
  int lane = tid & 63, wave = tid >> 6;
  int q8 = lane >> 4, nl = lane & 15;
  int bm = blockIdx.x * 256, bn = blockIdx.y * 64;
  int z = blockIdx.z;
  const u16* A = xb;
  const u16* Bmat = wb + (size_t)z * E_ * E_;
  u16* C = qkv + (size_t)z * M * E_;
  float scale = (z == 0) ? (0.125f * 1.44269504088896f) : 1.0f;

  // A: 1024 slots of 16B -> 4/thread (row=tid, chunk=j). B: 256 slots -> 1/thread.
  int chB = tid >> 6, rowB = tid & 63;
  const u16* gaRow = A + (size_t)(bm + tid) * E_;
  const u16* gbRow = Bmat + (size_t)(bn + rowB) * E_ + chB * 8;

#define STAGE(s, ko)                                          \
  do {                                                        \
    _Pragma("unroll") for (int j = 0; j < 4; ++j)             \
        async_copy16(gaRow + (ko) + j * 8, &As[s][j][tid][0]); \
    async_copy16(gbRow + (ko), &Bs[s][chB][rowB][0]);         \
  } while (0)

  const int NK = E_ / 32;   // 24
  STAGE(0, 0);

  f32x4 acc[4][4] = {};
  for (int ki = 0; ki < NK; ++ki) {
    int buf = ki & 1;
    __syncthreads();
    if (ki + 1 < NK) STAGE(buf ^ 1, (ki + 1) * 32);
    bf16x8 af[4], bfr[4];
#pragma unroll
    for (int i = 0; i < 4; ++i)
      af[i] = *(const bf16x8*)&As[buf][q8][wave * 64 + i * 16 + nl][0];
#pragma unroll
    for (int j = 0; j < 4; ++j)
      bfr[j] = *(const bf16x8*)&Bs[buf][q8][j * 16 + nl][0];
#pragma unroll
    for (int i = 0; i < 4; ++i)
#pragma unroll
      for (int j = 0; j < 4; ++j)
        acc[i][j] = __builtin_amdgcn_mfma_f32_16x16x32_bf16(af[i], bfr[j], acc[i][j], 0, 0, 0);
  }
#undef STAGE

#pragma unroll
  for (int i = 0; i < 4; ++i)
#pragma unroll
    for (int j = 0; j < 4; ++j)
#pragma unroll
      for (int r = 0; r < 4; ++r) {
        int row = bm + wave * 64 + i * 16 + q8 * 4 + r;
        int col = bn + j * 16 + nl;
        C[(size_t)row * E_ + col] = f2bf(acc[i][j][r] * scale);
      }
}

// ---------------- V transpose: v[b*T+t][e] -> vT[b][e][t] ----------------
__global__ void transpose_v(const u16* __restrict__ v, u16* __restrict__ vT) {
  __shared__ u16 lt[64][66];
  int t = threadIdx.x;
  int t0 = blockIdx.x * 64;
  int e0 = blockIdx.y * 64;
  int b = blockIdx.z;
#pragma unroll
  for (int i = 0; i < 2; ++i) {
    int u = t + i * 256;
    int tok = u >> 3, cg = u & 7;
    bf16x8 val = *(const bf16x8*)(v + (size_t)(b * T_ + t0 + tok) * E_ + e0 + cg * 8);
#pragma unroll
    for (int j = 0; j < 8; ++j) lt[tok][cg * 8 + j] = (u16)val[j];
  }
  __syncthreads();
#pragma unroll
  for (int i = 0; i < 2; ++i) {
    int u = t + i * 256;
    int d = u >> 3, ck = u & 7;
    bf16x8 o;
#pragma unroll
    for (int j = 0; j < 8; ++j) o[j] = (short)lt[ck * 8 + j][d];
    *(bf16x8*)(vT + (size_t)(b * E_ + e0 + d) * T_ + t0 + ck * 8) = o;
  }
}

// ---------------- banded flash attention: 32 q/wave, barrier-free (r3 version) ----------------
__global__ __launch_bounds__(256)
void attn_kernel(const u16* __restrict__ qkv, const u16* __restrict__ vT,
                 float* __restrict__ out) {
  const int Mtot = B_ * T_;
  const u16* qb = qkv;
  const u16* kb = qkv + (size_t)Mtot * E_;

  __shared__ u16 Pl[4][2][16][36];

  int tid = threadIdx.x;
  int lane = tid & 63, wave = tid >> 6;
  int q8 = lane >> 4, nl = lane & 15;
  int qs = blockIdx.x * 128;
  int bh = blockIdx.y;
  int b = bh / H_, h = bh % H_;
  int qw = qs + wave * 32;
  size_t ho = (size_t)h * S_;

  bf16x8 aq[2][2];
#pragma unroll
  for (int mt = 0; mt < 2; ++mt) {
    const u16* qrow = qb + (size_t)(b * T_ + qw + mt * 16 + nl) * E_ + ho;
    aq[mt][0] = *(const bf16x8*)(qrow + q8 * 8);
    aq[mt][1] = *(const bf16x8*)(qrow + 32 + q8 * 8);
  }

  f32x4 O[2][4] = {};
  f32x4 lacc[2] = {};

  int klo = qw - WIN_; if (klo < 0) klo = 0;
  int khi = qw + 32 + WIN_; if (khi > T_) khi = T_;

  const u16* kbase = kb + (size_t)b * T_ * E_ + ho;
  const u16* vbase = vT + (size_t)b * E_ * T_ + ho * T_;

  bf16x8 bk[2][2];
#pragma unroll
  for (int nt = 0; nt < 2; ++nt) {
    const u16* krow = kbase + (size_t)(klo + nt * 16 + nl) * E_;
    bk[nt][0] = *(const bf16x8*)(krow + q8 * 8);
    bk[nt][1] = *(const bf16x8*)(krow + 32 + q8 * 8);
  }

  for (int kt = klo; kt < khi; kt += 32) {
    bf16x8 bv[4];
#pragma unroll
    for (int dt = 0; dt < 4; ++dt)
      bv[dt] = *(const bf16x8*)(vbase + (size_t)(dt * 16 + nl) * T_ + kt + q8 * 8);

    int ktn = (kt + 32 < khi) ? kt + 32 : kt;
    bf16x8 nbk[2][2];
#pragma unroll
    for (int nt = 0; nt < 2; ++nt) {
      const u16* krow = kbase + (size_t)(ktn + nt * 16 + nl) * E_;
      nbk[nt][0] = *(const bf16x8*)(krow + q8 * 8);
      nbk[nt][1] = *(const bf16x8*)(krow + 32 + q8 * 8);
    }

    f32x4 sc[2][2] = {};
#pragma unroll
    for (int nt = 0; nt < 2; ++nt)
#pragma unroll
      for (int mt = 0; mt < 2; ++mt) {
        sc[mt][nt] = __builtin_amdgcn_mfma_f32_16x16x32_bf16(aq[mt][0], bk[nt][0], sc[mt][nt], 0, 0, 0);
        sc[mt][nt] = __builtin_amdgcn_mfma_f32_16x16x32_bf16(aq[mt][1], bk[nt][1], sc[mt][nt], 0, 0, 0);
      }

    if (kt < qw - 225 || kt > qw + 225) {
#pragma unroll
      for (int mt = 0; mt < 2; ++mt)
#pragma unroll
        for (int nt = 0; nt < 2; ++nt)
#pragma unroll
          for (int r = 0; r < 4; ++r) {
            int qa = qw + mt * 16 + q8 * 4 + r;
            int ka = kt + nt * 16 + nl;
            int d = ka - qa;
            sc[mt][nt][r] = (d < -WIN_ || d > WIN_) ? -1e30f : sc[mt][nt][r];
          }
    }

#pragma unroll
    for (int mt = 0; mt < 2; ++mt)
#pragma unroll
      for (int r = 0; r < 4; ++r) {
        float p0 = exp2f(sc[mt][0][r]);
        float p1 = exp2f(sc[mt][1][r]);
        sc[mt][0][r] = p0; sc[mt][1][r] = p1;
        lacc[mt][r] += p0 + p1;
      }

#pragma unroll
    for (int mt = 0; mt < 2; ++mt)
#pragma unroll
      for (int r = 0; r < 4; ++r) {
        Pl[wave][mt][q8 * 4 + r][nl] = f2bf(sc[mt][0][r]);
        Pl[wave][mt][q8 * 4 + r][16 + nl] = f2bf(sc[mt][1][r]);
      }

    bf16x8 ap[2];
#pragma unroll
    for (int mt = 0; mt < 2; ++mt) {
      bf16x4 lo = *(const bf16x4*)&Pl[wave][mt][nl][q8 * 8];
      bf16x4 hi = *(const bf16x4*)&Pl[wave][mt][nl][q8 * 8 + 4];
      bf16x8 a;
      a[0] = lo[0]; a[1] = lo[1]; a[2] = lo[2]; a[3] = lo[3];
      a[4] = hi[0]; a[5] = hi[1]; a[6] = hi[2]; a[7] = hi[3];
      ap[mt] = a;
    }

#pragma unroll
    for (int dt = 0; dt < 4; ++dt)
#pragma unroll
      for (int mt = 0; mt < 2; ++mt)
        O[mt][dt] = __builtin_amdgcn_mfma_f32_16x16x32_bf16(ap[mt], bv[dt], O[mt][dt], 0, 0, 0);

#pragma unroll
    for (int nt = 0; nt < 2; ++nt) {
      bk[nt][0] = nbk[nt][0];
      bk[nt][1] = nbk[nt][1];
    }
  }

#pragma unroll
  for (int mt = 0; mt < 2; ++mt)
#pragma unroll
    for (int r = 0; r < 4; ++r) {
      float l = lacc[mt][r];
      l += __shfl_xor(l, 1); l += __shfl_xor(l, 2);
      l += __shfl_xor(l, 4); l += __shfl_xor(l, 8);
      float inv = 1.0f / l;
      int qa = qw + mt * 16 + q8 * 4 + r;
      float* op = out + (size_t)(b * T_ + qa) * E_ + ho;
#pragma unroll
      for (int dt = 0; dt < 4; ++dt)
        op[dt * 16 + nl] = O[mt][dt][r] * inv;
    }
}

extern "C" void kernel_launch(void* const* d_in, const int* in_sizes, int n_in,
                              void* d_out, int out_size, void* d_ws, size_t ws_size,
                              hipStream_t stream) {
  const float* x  = (const float*)d_in[0];
  const float* Wq = (const float*)d_in[1];
  const float* Wk = (const float*)d_in[2];
  const float* Wv = (const float*)d_in[3];
  float* out = (float*)d_out;

  const size_t M = (size_t)B_ * T_;
  u16* xb  = (u16*)d_ws;               // M*E bf16; reused as vT after gemm
  u16* wb  = xb + M * E_;              // 3*E*E
  u16* qkv = wb + 3 * (size_t)E_ * E_; // 3*M*E
  u16* vT  = xb;                       // [B][E][T]

  const int n4x = B_ * T_ * E_ / 4;
  const int n4w = E_ * E_ / 4;
  int cvt_blocks = (n4x + 3 * n4w + 255) / 256;
  cvt_all<<<cvt_blocks, 256, 0, stream>>>(x, Wq, Wk, Wv, xb, wb);

  dim3 g1(M / 256, E_ / 64, 3);
  gemm_qkv<<<g1, 256, 0, stream>>>(xb, wb, qkv);

  dim3 gt(T_ / 64, E_ / 64, B_);
  transpose_v<<<gt, 256, 0, stream>>>(qkv + 2 * M * E_, vT);

  dim3 g2(T_ / 128, B_ * H_);
  attn_kernel<<<g2, 256, 0, stream>>>(qkv, vT, out);
}